// Round 6
// baseline (199.839 us; speedup 1.0000x reference)
//
#include <hip/hip_runtime.h>
#include <cstddef>

typedef __attribute__((ext_vector_type(8))) short short8;
typedef __attribute__((ext_vector_type(4))) float f4;
typedef __attribute__((ext_vector_type(4))) unsigned int u4;

__device__ __forceinline__ unsigned int f2bf(float f){
  unsigned int u = __float_as_uint(f);
  u += 0x7fffu + ((u >> 16) & 1u);   // RNE to bf16
  return u >> 16;
}
__device__ __forceinline__ float bflo(unsigned int w){ return __uint_as_float((w & 0xFFFFu) << 16); }
__device__ __forceinline__ float bfhi(unsigned int w){ return __uint_as_float(w & 0xFFFF0000u); }
__device__ __forceinline__ float fsign(float x){ return (x > 0.f) ? 1.f : ((x < 0.f) ? -1.f : 0.f); }
__device__ __forceinline__ float hclip(float x){ return fminf(1.f, fmaxf(-1.f, x)); }

// Raw workgroup barrier: drain ONLY lgkm (LDS) — global loads stay in flight.
#define BARRIER() do { \
    __builtin_amdgcn_sched_barrier(0); \
    asm volatile("s_waitcnt lgkmcnt(0)" ::: "memory"); \
    __builtin_amdgcn_s_barrier(); \
    asm volatile("" ::: "memory"); \
    __builtin_amdgcn_sched_barrier(0); \
  } while(0)

// ---------------- prep: sign(W1)+sign(W2) fp32 -> bf16 {+1,-1,0}, one dispatch ----------------
__global__ void prep_sign_k(const float* __restrict__ W1, unsigned short* __restrict__ w1s,
                            const float* __restrict__ W2, unsigned short* __restrict__ w2s){
  int i = (blockIdx.x * blockDim.x + threadIdx.x) * 8;
  const float* w; unsigned short* o; int off;
  if (i < 1048576){ w = W1; o = w1s; off = i; }
  else            { w = W2; o = w2s; off = i - 1048576; if (off >= 32768) return; }
  f4 a = *(const f4*)(w + off);
  f4 b = *(const f4*)(w + off + 4);
  unsigned short s[8];
  #pragma unroll
  for (int j = 0; j < 4; j++) s[j]   = (a[j] > 0.f) ? 0x3F80u : ((a[j] < 0.f) ? 0xBF80u : 0u);
  #pragma unroll
  for (int j = 0; j < 4; j++) s[4+j] = (b[j] > 0.f) ? 0x3F80u : ((b[j] < 0.f) ? 0xBF80u : 0u);
  u4 v;
  v.x = (unsigned)s[0] | ((unsigned)s[1] << 16);
  v.y = (unsigned)s[2] | ((unsigned)s[3] << 16);
  v.z = (unsigned)s[4] | ((unsigned)s[5] << 16);
  v.w = (unsigned)s[6] | ((unsigned)s[7] << 16);
  *(u4*)(o + off) = v;
}

// ---------------- GEMM1: h1(bf16) = x @ signW1^T + sign(b1), fused transposed col-stats ---------
// BM=32, BN=256, 256 thr = 4 waves (wave tile 32x64), grid 512 => 2 blocks/CU.
// Phase = 2 K-steps. Issue order per phase: [all 16 B-loads (L2)] then [4 A-loads (HBM)].
// In-order vmcnt: B-waits never drain A; only the phase-end LDS write waits for A.
__global__ __launch_bounds__(256, 2) void gemm1_k(
    const float* __restrict__ x, const unsigned short* __restrict__ w1s,
    const float* __restrict__ b1, unsigned short* __restrict__ h1,
    float* __restrict__ part1s, float* __restrict__ part1q)
{
  __shared__ __align__(16) char lds[16384];   // 2 phase-halves x 2 steps x 4KB
  const int tid  = threadIdx.x;
  const int lane = tid & 63;
  const int wid  = tid >> 6;          // 0..3 -> cols wid*64..+63
  const int cl   = lane & 15;
  const int g    = lane >> 4;         // 0..3
  const int klo  = g * 8;
  const int row0 = blockIdx.x * 32;

  // A staging: thread -> row am (0..31), 8 contiguous k at ak0
  const int am  = tid >> 3;
  const int ak0 = (tid & 7) * 8;
  const float* xA = x + (size_t)(row0 + am) * 4096 + ak0;
  const int aoff  = ((am * 128) + (ak0 * 2)) ^ ((am & 7) << 4);

  // B direct-load base: row n = wid*64 + cl (+fn*16), k = klo (+ks*32)
  const unsigned short* wbase = w1s + (size_t)(wid * 64 + cl) * 4096 + klo;

  f4 acc[2][4];
  const f4 z = {0.f, 0.f, 0.f, 0.f};
  #pragma unroll
  for (int i = 0; i < 2; i++)
    #pragma unroll
    for (int j = 0; j < 4; j++) acc[i][j] = z;

  f4 rA0a, rA0b, rA1a, rA1b;                    // A regs for 2 steps
  short8 BB0_0, BB0_1, BB0_2, BB0_3, BB0_4, BB0_5, BB0_6, BB0_7;   // B step0: fn0..3 x ks0..1
  short8 BB1_0, BB1_1, BB1_2, BB1_3, BB1_4, BB1_5, BB1_6, BB1_7;   // B step1

#define LOADB8(S, KB) do { \
    BB##S##_0 = *(const short8*)(wbase +          (KB)*64     ); \
    BB##S##_1 = *(const short8*)(wbase +          (KB)*64 + 32); \
    BB##S##_2 = *(const short8*)(wbase +  65536 + (KB)*64     ); \
    BB##S##_3 = *(const short8*)(wbase +  65536 + (KB)*64 + 32); \
    BB##S##_4 = *(const short8*)(wbase + 131072 + (KB)*64     ); \
    BB##S##_5 = *(const short8*)(wbase + 131072 + (KB)*64 + 32); \
    BB##S##_6 = *(const short8*)(wbase + 196608 + (KB)*64     ); \
    BB##S##_7 = *(const short8*)(wbase + 196608 + (KB)*64 + 32); \
  } while(0)

#define LOADA2(KB0) do { \
    rA0a = *(const f4*)(xA + (KB0+0)*64); rA0b = *(const f4*)(xA + (KB0+0)*64 + 4); \
    rA1a = *(const f4*)(xA + (KB0+1)*64); rA1b = *(const f4*)(xA + (KB0+1)*64 + 4); \
  } while(0)

#define PACK1(DST, RA, RB) do { \
    u4 _v; \
    _v.x = f2bf(RA[0]) | (f2bf(RA[1]) << 16); \
    _v.y = f2bf(RA[2]) | (f2bf(RA[3]) << 16); \
    _v.z = f2bf(RB[0]) | (f2bf(RB[1]) << 16); \
    _v.w = f2bf(RB[2]) | (f2bf(RB[3]) << 16); \
    *(u4*)(DST) = _v; \
  } while(0)

#define WRITEA2(WB) do { \
    PACK1((WB) +    0 + aoff, rA0a, rA0b); \
    PACK1((WB) + 4096 + aoff, rA1a, rA1b); \
  } while(0)

#define COMPUTE1(BASE, S) do { \
    const char* _ab = (const char*)(BASE); \
    short8 _a0k0, _a0k1, _a1k0, _a1k1; \
    { int _m = cl; \
      _a0k0 = *(const short8*)(_ab + ((_m*128 +      klo*2) ^ ((_m & 7) << 4))); \
      _a0k1 = *(const short8*)(_ab + ((_m*128 + 64 + klo*2) ^ ((_m & 7) << 4))); } \
    { int _m = 16 + cl; \
      _a1k0 = *(const short8*)(_ab + ((_m*128 +      klo*2) ^ ((_m & 7) << 4))); \
      _a1k1 = *(const short8*)(_ab + ((_m*128 + 64 + klo*2) ^ ((_m & 7) << 4))); } \
    acc[0][0] = __builtin_amdgcn_mfma_f32_16x16x32_bf16(_a0k0, BB##S##_0, acc[0][0], 0, 0, 0); \
    acc[0][1] = __builtin_amdgcn_mfma_f32_16x16x32_bf16(_a0k0, BB##S##_2, acc[0][1], 0, 0, 0); \
    acc[0][2] = __builtin_amdgcn_mfma_f32_16x16x32_bf16(_a0k0, BB##S##_4, acc[0][2], 0, 0, 0); \
    acc[0][3] = __builtin_amdgcn_mfma_f32_16x16x32_bf16(_a0k0, BB##S##_6, acc[0][3], 0, 0, 0); \
    acc[1][0] = __builtin_amdgcn_mfma_f32_16x16x32_bf16(_a1k0, BB##S##_0, acc[1][0], 0, 0, 0); \
    acc[1][1] = __builtin_amdgcn_mfma_f32_16x16x32_bf16(_a1k0, BB##S##_2, acc[1][1], 0, 0, 0); \
    acc[1][2] = __builtin_amdgcn_mfma_f32_16x16x32_bf16(_a1k0, BB##S##_4, acc[1][2], 0, 0, 0); \
    acc[1][3] = __builtin_amdgcn_mfma_f32_16x16x32_bf16(_a1k0, BB##S##_6, acc[1][3], 0, 0, 0); \
    acc[0][0] = __builtin_amdgcn_mfma_f32_16x16x32_bf16(_a0k1, BB##S##_1, acc[0][0], 0, 0, 0); \
    acc[0][1] = __builtin_amdgcn_mfma_f32_16x16x32_bf16(_a0k1, BB##S##_3, acc[0][1], 0, 0, 0); \
    acc[0][2] = __builtin_amdgcn_mfma_f32_16x16x32_bf16(_a0k1, BB##S##_5, acc[0][2], 0, 0, 0); \
    acc[0][3] = __builtin_amdgcn_mfma_f32_16x16x32_bf16(_a0k1, BB##S##_7, acc[0][3], 0, 0, 0); \
    acc[1][0] = __builtin_amdgcn_mfma_f32_16x16x32_bf16(_a1k1, BB##S##_1, acc[1][0], 0, 0, 0); \
    acc[1][1] = __builtin_amdgcn_mfma_f32_16x16x32_bf16(_a1k1, BB##S##_3, acc[1][1], 0, 0, 0); \
    acc[1][2] = __builtin_amdgcn_mfma_f32_16x16x32_bf16(_a1k1, BB##S##_5, acc[1][2], 0, 0, 0); \
    acc[1][3] = __builtin_amdgcn_mfma_f32_16x16x32_bf16(_a1k1, BB##S##_7, acc[1][3], 0, 0, 0); \
  } while(0)

  // prologue: stage phase 0's A
  LOADA2(0);
  WRITEA2(lds);
  BARRIER();

  for (int p = 0; p < 32; ++p){
    char* rb = lds + ((p & 1) << 13);
    char* wb = lds + (((p & 1) ^ 1) << 13);
    LOADB8(0, 2*p);                      // B first (older than A) — B-waits never drain A
    LOADB8(1, 2*p + 1);
    __builtin_amdgcn_sched_barrier(0);
    if (p < 31) LOADA2(2*p + 2);         // A last (newest)
    __builtin_amdgcn_sched_barrier(0);
    COMPUTE1(rb,        0);
    COMPUTE1(rb + 4096, 1);
    __builtin_amdgcn_sched_barrier(0);
    if (p < 31) WRITEA2(wb);             // counted vmcnt wait for A only
    BARRIER();
  }
#undef COMPUTE1
#undef WRITEA2
#undef PACK1
#undef LOADA2
#undef LOADB8

  // epilogue: bf16 h1 write + fused transposed column stats
  #pragma unroll
  for (int fn = 0; fn < 4; fn++){
    int c = wid*64 + fn*16 + cl;
    float sb = fsign(b1[c]);
    float s = 0.f, q = 0.f;
    #pragma unroll
    for (int fm = 0; fm < 2; fm++){
      int rbase = row0 + fm*16 + g*4;
      #pragma unroll
      for (int i = 0; i < 4; i++){
        float v = acc[fm][fn][i] + sb;
        h1[(size_t)(rbase + i)*256 + c] = (unsigned short)f2bf(v);
        s += v; q += v*v;
      }
    }
    s += __shfl_xor(s, 16, 64); s += __shfl_xor(s, 32, 64);
    q += __shfl_xor(q, 16, 64); q += __shfl_xor(q, 32, 64);
    if (g == 0){
      part1s[c*512 + blockIdx.x] = s;
      part1q[c*512 + blockIdx.x] = q;
    }
  }
}

// ---------------- GEMM2: h2(bf16) = clip(BN1(h1)) @ signW2^T + sign(b2), fused stats -----------
// BN1 params computed redundantly per block from partials (L2-hit). BM=64, BN=128, K=256,
// 512 thr = 8 waves (wave tile 64x16), whole A-tile staged once, 3 barriers total.
__global__ __launch_bounds__(512) void gemm2_k(
    const unsigned short* __restrict__ h1, const unsigned short* __restrict__ w2s,
    const float* __restrict__ b2,
    const float* __restrict__ part1s, const float* __restrict__ part1q,
    const float* __restrict__ g1, const float* __restrict__ be1,
    unsigned short* __restrict__ h2, float* __restrict__ part2s, float* __restrict__ part2q)
{
  __shared__ __align__(16) char lds[32768];
  __shared__ __align__(16) float a1l[256];
  __shared__ __align__(16) float c1l[256];
  __shared__ __align__(16) float sred[512];
  __shared__ __align__(16) float qred[512];
  const int tid  = threadIdx.x;
  const int lane = tid & 63;
  const int wid  = tid >> 6;          // 0..7 -> cols wid*16..+15
  const int cl   = lane & 15;
  const int g    = lane >> 4;
  const int klo  = g * 8;
  const int row0 = blockIdx.x * 64;

  const int am  = tid >> 3;
  const int ak0 = (tid & 7) * 8;
  const unsigned short* hA = h1 + (size_t)(row0 + am) * 256 + ak0;
  const int aw = ((am * 128) + (ak0 * 2)) ^ ((am & 7) << 4);
  const unsigned short* wbase = w2s + (size_t)(wid * 16 + cl) * 256 + klo;

  // issue h1 tile + first B loads up front (oldest in vmem queue)
  u4 q0 = *(const u4*)(hA);
  u4 q1 = *(const u4*)(hA + 64);
  u4 q2 = *(const u4*)(hA + 128);
  u4 q3 = *(const u4*)(hA + 192);
  short8 Bq0, Bq1, Br0, Br1;
  Bq0 = *(const short8*)(wbase);
  Bq1 = *(const short8*)(wbase + 32);

  // redundant BN1 param reduce: (col, half) over 256 partials each
  {
    const int col = tid & 255, half = tid >> 8;
    const f4* vs = (const f4*)(part1s + col*512 + half*256);
    const f4* vq = (const f4*)(part1q + col*512 + half*256);
    f4 s4 = {0,0,0,0}, q4 = {0,0,0,0};
    #pragma unroll 8
    for (int b = 0; b < 64; b++){ s4 += vs[b]; q4 += vq[b]; }
    sred[tid] = s4[0]+s4[1]+s4[2]+s4[3];
    qred[tid] = q4[0]+q4[1]+q4[2]+q4[3];
  }
  BARRIER();
  if (tid < 256){
    float s = sred[tid] + sred[256 + tid];
    float q = qred[tid] + qred[256 + tid];
    float mu  = s * (1.f/16384.f);
    float var = q * (1.f/16384.f) - mu*mu;
    float a   = g1[tid] * rsqrtf(var + 1e-5f);
    a1l[tid] = a;
    c1l[tid] = be1[tid] - mu*a;
  }
  BARRIER();

#define TRW(KB, RAW) do { \
    f4 _a0 = *(const f4*)(&a1l[(KB)*64 + ak0]); \
    f4 _a1 = *(const f4*)(&a1l[(KB)*64 + ak0 + 4]); \
    f4 _c0 = *(const f4*)(&c1l[(KB)*64 + ak0]); \
    f4 _c1 = *(const f4*)(&c1l[(KB)*64 + ak0 + 4]); \
    float _t0 = hclip(_a0[0]*bflo(RAW.x) + _c0[0]); \
    float _t1 = hclip(_a0[1]*bfhi(RAW.x) + _c0[1]); \
    float _t2 = hclip(_a0[2]*bflo(RAW.y) + _c0[2]); \
    float _t3 = hclip(_a0[3]*bfhi(RAW.y) + _c0[3]); \
    float _t4 = hclip(_a1[0]*bflo(RAW.z) + _c1[0]); \
    float _t5 = hclip(_a1[1]*bfhi(RAW.z) + _c1[1]); \
    float _t6 = hclip(_a1[2]*bflo(RAW.w) + _c1[2]); \
    float _t7 = hclip(_a1[3]*bfhi(RAW.w) + _c1[3]); \
    u4 _v; \
    _v.x = f2bf(_t0) | (f2bf(_t1) << 16); \
    _v.y = f2bf(_t2) | (f2bf(_t3) << 16); \
    _v.z = f2bf(_t4) | (f2bf(_t5) << 16); \
    _v.w = f2bf(_t6) | (f2bf(_t7) << 16); \
    *(u4*)(lds + (KB)*8192 + aw) = _v; \
  } while(0)

  TRW(0, q0); TRW(1, q1); TRW(2, q2); TRW(3, q3);
#undef TRW
  BARRIER();

  f4 acc[4];
  const f4 z = {0.f, 0.f, 0.f, 0.f};
  #pragma unroll
  for (int i = 0; i < 4; i++) acc[i] = z;

#define LOADB2(P, KB) do { \
    B##P##0 = *(const short8*)(wbase + (KB)*64); \
    B##P##1 = *(const short8*)(wbase + (KB)*64 + 32); \
  } while(0)

#define COMP2(BASE, P) do { \
    const char* _ab = (const char*)(BASE); \
    short8 _af[4][2]; \
    _Pragma("unroll") \
    for (int fm = 0; fm < 4; fm++){ \
      int _m = fm*16 + cl; \
      _af[fm][0] = *(const short8*)(_ab + ((_m*128 + klo*2) ^ ((_m & 7) << 4))); \
      _af[fm][1] = *(const short8*)(_ab + ((_m*128 + (32 + klo)*2) ^ ((_m & 7) << 4))); \
    } \
    _Pragma("unroll") \
    for (int fm = 0; fm < 4; fm++){ \
      acc[fm] = __builtin_amdgcn_mfma_f32_16x16x32_bf16(_af[fm][0], B##P##0, acc[fm], 0, 0, 0); \
      acc[fm] = __builtin_amdgcn_mfma_f32_16x16x32_bf16(_af[fm][1], B##P##1, acc[fm], 0, 0, 0); \
    } \
  } while(0)

  LOADB2(r, 1);
  COMP2(lds,         q);
  LOADB2(q, 2);
  COMP2(lds +  8192, r);
  LOADB2(r, 3);
  COMP2(lds + 16384, q);
  COMP2(lds + 24576, r);
#undef COMP2
#undef LOADB2

  {
    int c = wid*16 + cl;
    float sb = fsign(b2[c]);
    float s = 0.f, q = 0.f;
    #pragma unroll
    for (int fm = 0; fm < 4; fm++){
      int rbase = row0 + fm*16 + g*4;
      #pragma unroll
      for (int i = 0; i < 4; i++){
        float v = acc[fm][i] + sb;
        h2[(size_t)(rbase + i)*128 + c] = (unsigned short)f2bf(v);
        s += v; q += v*v;
      }
    }
    s += __shfl_xor(s, 16, 64); s += __shfl_xor(s, 32, 64);
    q += __shfl_xor(q, 16, 64); q += __shfl_xor(q, 32, 64);
    if (g == 0){
      part2s[c*256 + blockIdx.x] = s;
      part2q[c*256 + blockIdx.x] = q;
    }
  }
}

// ---------------- final: out = clip(BN2(h2)) @ W4^T + b4, BN2 params fused ---------------------
// 128 blocks x 128 thr; prologue: per-thread column reduce of part2 (L2-hit); then row work.
__global__ __launch_bounds__(128) void final_k(
    const unsigned short* __restrict__ h2,
    const float* __restrict__ part2s, const float* __restrict__ part2q,
    const float* __restrict__ g2, const float* __restrict__ be2,
    const float* __restrict__ W4, const float* __restrict__ b4,
    float* __restrict__ out)
{
  __shared__ __align__(16) float W4l[12*128];
  __shared__ __align__(16) float a2l[128];
  __shared__ __align__(16) float c2l[128];
  const int t = threadIdx.x;
  #pragma unroll
  for (int i = 0; i < 3; i++)
    *(f4*)&W4l[(i*128 + t)*4] = *(const f4*)(W4 + (i*128 + t)*4);
  {
    const f4* vs = (const f4*)(part2s + t*256);
    const f4* vq = (const f4*)(part2q + t*256);
    f4 s4 = {0,0,0,0}, q4 = {0,0,0,0};
    #pragma unroll 8
    for (int b = 0; b < 64; b++){ s4 += vs[b]; q4 += vq[b]; }
    float s = s4[0]+s4[1]+s4[2]+s4[3];
    float q = q4[0]+q4[1]+q4[2]+q4[3];
    float mu  = s * (1.f/16384.f);
    float var = q * (1.f/16384.f) - mu*mu;
    float a   = g2[t] * rsqrtf(var + 1e-5f);
    a2l[t] = a;
    c2l[t] = be2[t] - mu*a;
  }
  __syncthreads();

  const int r = blockIdx.x * 128 + t;
  const u4* hp = (const u4*)(h2 + (size_t)r * 128);
  u4 hv0 = hp[0], hv1 = hp[1], hv2 = hp[2],  hv3 = hp[3];
  u4 hv4 = hp[4], hv5 = hp[5], hv6 = hp[6],  hv7 = hp[7];
  u4 hv8 = hp[8], hv9 = hp[9], hv10 = hp[10], hv11 = hp[11];
  u4 hv12 = hp[12], hv13 = hp[13], hv14 = hp[14], hv15 = hp[15];

  float acc[12];
  #pragma unroll
  for (int o = 0; o < 12; o++) acc[o] = b4[o];

#define FPROC(HV, J) do { \
    f4 a0 = *(const f4*)&a2l[(J)*8];     f4 a1 = *(const f4*)&a2l[(J)*8 + 4]; \
    f4 c0 = *(const f4*)&c2l[(J)*8];     f4 c1 = *(const f4*)&c2l[(J)*8 + 4]; \
    float tt0 = hclip(a0[0]*bflo(HV.x) + c0[0]); \
    float tt1 = hclip(a0[1]*bfhi(HV.x) + c0[1]); \
    float tt2 = hclip(a0[2]*bflo(HV.y) + c0[2]); \
    float tt3 = hclip(a0[3]*bfhi(HV.y) + c0[3]); \
    float tt4 = hclip(a1[0]*bflo(HV.z) + c1[0]); \
    float tt5 = hclip(a1[1]*bfhi(HV.z) + c1[1]); \
    float tt6 = hclip(a1[2]*bflo(HV.w) + c1[2]); \
    float tt7 = hclip(a1[3]*bfhi(HV.w) + c1[3]); \
    _Pragma("unroll") \
    for (int o = 0; o < 12; o++){ \
      f4 w0 = *(const f4*)&W4l[o*128 + (J)*8]; \
      f4 w1 = *(const f4*)&W4l[o*128 + (J)*8 + 4]; \
      acc[o] += tt0*w0[0] + tt1*w0[1] + tt2*w0[2] + tt3*w0[3] \
              + tt4*w1[0] + tt5*w1[1] + tt6*w1[2] + tt7*w1[3]; \
    } \
  } while(0)

  FPROC(hv0, 0);  FPROC(hv1, 1);  FPROC(hv2, 2);   FPROC(hv3, 3);
  FPROC(hv4, 4);  FPROC(hv5, 5);  FPROC(hv6, 6);   FPROC(hv7, 7);
  FPROC(hv8, 8);  FPROC(hv9, 9);  FPROC(hv10, 10); FPROC(hv11, 11);
  FPROC(hv12, 12); FPROC(hv13, 13); FPROC(hv14, 14); FPROC(hv15, 15);
#undef FPROC

  #pragma unroll
  for (int o = 0; o < 12; o++) out[(size_t)r*12 + o] = acc[o];
}

// ---------------- launch ----------------
extern "C" void kernel_launch(void* const* d_in, const int* in_sizes, int n_in,
                              void* d_out, int out_size, void* d_ws, size_t ws_size,
                              hipStream_t stream)
{
  const float* x   = (const float*)d_in[0];
  const float* W1  = (const float*)d_in[1];
  const float* b1  = (const float*)d_in[2];
  const float* g1  = (const float*)d_in[3];
  const float* be1 = (const float*)d_in[4];
  const float* W2  = (const float*)d_in[5];
  const float* b2  = (const float*)d_in[6];
  const float* g2  = (const float*)d_in[7];
  const float* be2 = (const float*)d_in[8];
  const float* W4  = (const float*)d_in[9];
  const float* b4  = (const float*)d_in[10];
  float* out = (float*)d_out;

  char* ws = (char*)d_ws;
  unsigned short* h1     = (unsigned short*)(ws);              //  8 MB  [16384,256] bf16
  unsigned short* h2     = (unsigned short*)(ws + 8388608);    //  4 MB  [16384,128] bf16
  unsigned short* w1s    = (unsigned short*)(ws + 12582912);   //  2 MB  [256,4096] bf16
  unsigned short* w2s    = (unsigned short*)(ws + 14680064);   // 64 KB  [128,256] bf16
  float*          part1s = (float*)(ws + 14745600);            // 512 KB [256][512]
  float*          part1q = (float*)(ws + 15269888);            // 512 KB
  float*          part2s = (float*)(ws + 15794176);            // 128 KB [128][256]
  float*          part2q = (float*)(ws + 15925248);            // 128 KB

  prep_sign_k<<<528, 256, 0, stream>>>(W1, w1s, W2, w2s);
  gemm1_k<<<512, 256, 0, stream>>>(x, w1s, b1, h1, part1s, part1q);
  gemm2_k<<<256, 512, 0, stream>>>(h1, w2s, b2, part1s, part1q, g1, be1, h2, part2s, part2q);
  final_k<<<128, 128, 0, stream>>>(h2, part2s, part2q, g2, be2, W4, b4, out);
}

// Round 7
// 120.577 us; speedup vs baseline: 1.6574x; 1.6574x over previous
//
#include <hip/hip_runtime.h>
#include <cstddef>

typedef __attribute__((ext_vector_type(8))) short short8;
typedef __attribute__((ext_vector_type(4))) float f4;
typedef __attribute__((ext_vector_type(4))) unsigned int u4;

__device__ __forceinline__ unsigned int f2bf(float f){
  unsigned int u = __float_as_uint(f);
  u += 0x7fffu + ((u >> 16) & 1u);   // RNE to bf16
  return u >> 16;
}
__device__ __forceinline__ float bflo(unsigned int w){ return __uint_as_float((w & 0xFFFFu) << 16); }
__device__ __forceinline__ float bfhi(unsigned int w){ return __uint_as_float(w & 0xFFFF0000u); }
__device__ __forceinline__ float fsign(float x){ return (x > 0.f) ? 1.f : ((x < 0.f) ? -1.f : 0.f); }
__device__ __forceinline__ float hclip(float x){ return fminf(1.f, fmaxf(-1.f, x)); }

// lgkm-only barrier (for reg-staged LDS writes; vmem loads stay in flight)
#define BARRIER() do { \
    __builtin_amdgcn_sched_barrier(0); \
    asm volatile("s_waitcnt lgkmcnt(0)" ::: "memory"); \
    __builtin_amdgcn_s_barrier(); \
    asm volatile("" ::: "memory"); \
    __builtin_amdgcn_sched_barrier(0); \
  } while(0)

// counted-vmcnt barrier (for global_load_lds pipelines): drain all but N newest vmem ops
#define VBAR(N) do { \
    __builtin_amdgcn_sched_barrier(0); \
    asm volatile("s_waitcnt vmcnt(" #N ") lgkmcnt(0)" ::: "memory"); \
    __builtin_amdgcn_s_barrier(); \
    asm volatile("" ::: "memory"); \
    __builtin_amdgcn_sched_barrier(0); \
  } while(0)

// global -> LDS direct DMA, 16B per lane
#define GL16(gp, lp) __builtin_amdgcn_global_load_lds( \
    (const __attribute__((address_space(1))) void*)(gp), \
    (__attribute__((address_space(3))) void*)(lp), 16, 0, 0)

// ---------------- prep: sign(W1)+sign(W2) fp32 -> bf16 {+1,-1,0}, one dispatch ----------------
__global__ void prep_sign_k(const float* __restrict__ W1, unsigned short* __restrict__ w1s,
                            const float* __restrict__ W2, unsigned short* __restrict__ w2s){
  int i = (blockIdx.x * blockDim.x + threadIdx.x) * 8;
  const float* w; unsigned short* o; int off;
  if (i < 1048576){ w = W1; o = w1s; off = i; }
  else            { w = W2; o = w2s; off = i - 1048576; if (off >= 32768) return; }
  f4 a = *(const f4*)(w + off);
  f4 b = *(const f4*)(w + off + 4);
  unsigned short s[8];
  #pragma unroll
  for (int j = 0; j < 4; j++) s[j]   = (a[j] > 0.f) ? 0x3F80u : ((a[j] < 0.f) ? 0xBF80u : 0u);
  #pragma unroll
  for (int j = 0; j < 4; j++) s[4+j] = (b[j] > 0.f) ? 0x3F80u : ((b[j] < 0.f) ? 0xBF80u : 0u);
  u4 v;
  v.x = (unsigned)s[0] | ((unsigned)s[1] << 16);
  v.y = (unsigned)s[2] | ((unsigned)s[3] << 16);
  v.z = (unsigned)s[4] | ((unsigned)s[5] << 16);
  v.w = (unsigned)s[6] | ((unsigned)s[7] << 16);
  *(u4*)(o + off) = v;
}

// ---------------- GEMM1: h1(bf16) = x @ signW1^T + sign(b1), fused transposed col-stats ---------
// BM=64, BN=256, BK=64. 512 thr = 8 waves, wave tile 32x64 (wm=wid>>2, wn=wid&3).
// A (fp32) and B (bf16) both staged via global_load_lds with pre-swizzled global source;
// triple-buffered LDS (3 x (16KB A + 32KB B) = 144KB); counted-vmcnt barriers (stage k+2
// stays in flight across the barrier) -> HBM queue never drains. A converted fp32->bf16
// at frag-read (VALU has headroom). XOR-swizzled ds_read_b128 (2-way max, free).
__global__ __launch_bounds__(512, 1) void gemm1_k(
    const float* __restrict__ x, const unsigned short* __restrict__ w1s,
    const float* __restrict__ b1, unsigned short* __restrict__ h1,
    float* __restrict__ part1s, float* __restrict__ part1q)
{
  __shared__ __align__(16) char lds[147456];   // A: 3x16KB @0; B: 3x32KB @49152
  const int tid  = threadIdx.x;
  const int lane = tid & 63;
  const int wid  = tid >> 6;
  const int wm   = wid >> 2;          // 0..1 -> rows wm*32..+31
  const int wn   = wid & 3;           // 0..3 -> cols wn*64..+63
  const int cl   = lane & 15;
  const int g    = lane >> 4;         // 0..3
  const int row0 = blockIdx.x * 64;

  // stage-side (linear LDS dest, inverse-swizzled global source)
  const int aoff_o = tid * 16;        // + chunk*8192, within 16KB A buffer
  const int boff_o = tid * 16;        // + chunk*8192, within 32KB B buffer

  f4 acc[2][4];
  const f4 z = {0.f, 0.f, 0.f, 0.f};
  #pragma unroll
  for (int i = 0; i < 2; i++)
    #pragma unroll
    for (int j = 0; j < 4; j++) acc[i][j] = z;

  auto stage = [&](int buf, int kstep){
    char* abuf = lds + buf * 16384;
    char* bbuf = lds + 49152 + buf * 32768;
    // A: tile [64 rows][64 k] fp32, row=256B; element at lds-linear o comes from
    // within-row byte (o&255)^((m&7)<<5)
    #pragma unroll
    for (int c = 0; c < 2; c++){
      int o  = c * 8192 + aoff_o;
      int m  = o >> 8;
      int kb = (o & 255) ^ ((m & 7) << 5);
      const char* src = (const char*)x + (size_t)(row0 + m) * 16384 + kstep * 256 + kb;
      GL16(src, abuf + o);
    }
    // B: tile [256 n][64 k] bf16, row=128B; source byte (o&127)^((n&7)<<4)
    #pragma unroll
    for (int c = 0; c < 4; c++){
      int o  = c * 8192 + boff_o;
      int n  = o >> 7;
      int kb = (o & 127) ^ ((n & 7) << 4);
      const char* src = (const char*)w1s + (size_t)n * 8192 + kstep * 128 + kb;
      GL16(src, bbuf + o);
    }
  };

  auto compute = [&](int buf){
    const char* abuf = lds + buf * 16384;
    const char* bbuf = lds + 49152 + buf * 32768;
    short8 bf[4][2];
    #pragma unroll
    for (int fn = 0; fn < 4; fn++){
      int n = wn * 64 + fn * 16 + cl;
      #pragma unroll
      for (int ks = 0; ks < 2; ks++){
        int off = (n * 128 + ks * 64 + g * 16) ^ ((n & 7) << 4);
        bf[fn][ks] = *(const short8*)(bbuf + off);
      }
    }
    short8 af[2][2];
    #pragma unroll
    for (int fm = 0; fm < 2; fm++){
      int m = wm * 32 + fm * 16 + cl;
      #pragma unroll
      for (int ks = 0; ks < 2; ks++){
        int off = (m * 256 + ks * 128 + g * 32) ^ ((m & 7) << 5);
        f4 lo = *(const f4*)(abuf + off);
        f4 hi = *(const f4*)(abuf + off + 16);
        u4 pk;
        pk.x = f2bf(lo[0]) | (f2bf(lo[1]) << 16);
        pk.y = f2bf(lo[2]) | (f2bf(lo[3]) << 16);
        pk.z = f2bf(hi[0]) | (f2bf(hi[1]) << 16);
        pk.w = f2bf(hi[2]) | (f2bf(hi[3]) << 16);
        af[fm][ks] = *(short8*)&pk;
      }
    }
    #pragma unroll
    for (int ks = 0; ks < 2; ks++)
      #pragma unroll
      for (int fm = 0; fm < 2; fm++)
        #pragma unroll
        for (int fn = 0; fn < 4; fn++)
          acc[fm][fn] = __builtin_amdgcn_mfma_f32_16x16x32_bf16(af[fm][ks], bf[fn][ks], acc[fm][fn], 0, 0, 0);
  };

  // prologue: two stages in flight, drain the first only
  stage(0, 0);
  stage(1, 1);
  VBAR(6);
  int cb = 0;
  for (int k = 0; k < 64; ++k){
    int sb = cb + 2; if (sb >= 3) sb -= 3;
    if (k < 62) stage(sb, k + 2);       // 6 global_load_lds, newest in queue
    compute(cb);
    if (k < 62)      VBAR(6);           // drain stage(k+1), keep stage(k+2) in flight
    else if (k < 63) VBAR(0);           // last drain before final step
    cb = (cb == 2) ? 0 : cb + 1;
  }

  // epilogue: bf16 h1 write + fused transposed column stats (per block,wm partials)
  #pragma unroll
  for (int fn = 0; fn < 4; fn++){
    int c = wn * 64 + fn * 16 + cl;
    float sb = fsign(b1[c]);
    float s = 0.f, q = 0.f;
    #pragma unroll
    for (int fm = 0; fm < 2; fm++){
      int rbase = row0 + wm * 32 + fm * 16 + g * 4;
      #pragma unroll
      for (int i = 0; i < 4; i++){
        float v = acc[fm][fn][i] + sb;
        h1[(size_t)(rbase + i) * 256 + c] = (unsigned short)f2bf(v);
        s += v; q += v * v;
      }
    }
    s += __shfl_xor(s, 16, 64); s += __shfl_xor(s, 32, 64);
    q += __shfl_xor(q, 16, 64); q += __shfl_xor(q, 32, 64);
    if (g == 0){
      part1s[c * 512 + blockIdx.x * 2 + wm] = s;
      part1q[c * 512 + blockIdx.x * 2 + wm] = q;
    }
  }
}

// ---------------- BN params from transposed partials ------------------------------------------
template<int COLS, int NBLK>
__global__ __launch_bounds__(64) void params_k(
    const float* __restrict__ ps, const float* __restrict__ pq,
    const float* __restrict__ g, const float* __restrict__ be,
    float* __restrict__ ab){
  int j = blockIdx.x * 64 + threadIdx.x;
  const f4* vs = (const f4*)(ps + (size_t)j * NBLK);
  const f4* vq = (const f4*)(pq + (size_t)j * NBLK);
  f4 s4 = {0,0,0,0}, q4 = {0,0,0,0};
  #pragma unroll 8
  for (int b = 0; b < NBLK/4; b++){ s4 += vs[b]; q4 += vq[b]; }
  float s = s4[0]+s4[1]+s4[2]+s4[3];
  float q = q4[0]+q4[1]+q4[2]+q4[3];
  float mu  = s * (1.f/16384.f);
  float var = q * (1.f/16384.f) - mu*mu;
  float a   = g[j] * rsqrtf(var + 1e-5f);
  ab[j] = a;
  ab[COLS + j] = be[j] - mu*a;
}

// ---------------- GEMM2: h2(bf16) = clip(BN1(h1)) @ signW2^T + sign(b2), fused stats -----------
// BM=64, BN=128, K=256, 512 thr = 8 waves, wave tile 64x16. Whole A-tile staged once
// (reg-staged with BN transform), B direct from L2-hot 64KB, lgkm-only barriers.
__global__ __launch_bounds__(512) void gemm2_k(
    const unsigned short* __restrict__ h1, const unsigned short* __restrict__ w2s,
    const float* __restrict__ b2, const float* __restrict__ ab1,
    unsigned short* __restrict__ h2, float* __restrict__ part2s, float* __restrict__ part2q)
{
  __shared__ __align__(16) char lds[32768];
  __shared__ __align__(16) float a1l[256];
  __shared__ __align__(16) float c1l[256];
  const int tid  = threadIdx.x;
  const int lane = tid & 63;
  const int wid  = tid >> 6;          // 0..7 -> cols wid*16..+15
  const int cl   = lane & 15;
  const int g    = lane >> 4;
  const int klo  = g * 8;
  const int row0 = blockIdx.x * 64;

  if (tid < 256) a1l[tid] = ab1[tid];
  else           c1l[tid - 256] = ab1[tid];

  const int am  = tid >> 3;
  const int ak0 = (tid & 7) * 8;
  const unsigned short* hA = h1 + (size_t)(row0 + am) * 256 + ak0;
  const int aw = ((am * 128) + (ak0 * 2)) ^ ((am & 7) << 4);
  const unsigned short* wbase = w2s + (size_t)(wid * 16 + cl) * 256 + klo;

  // issue h1 tile + first B loads up front
  u4 q0 = *(const u4*)(hA);
  u4 q1 = *(const u4*)(hA + 64);
  u4 q2 = *(const u4*)(hA + 128);
  u4 q3 = *(const u4*)(hA + 192);
  short8 Bq0, Bq1, Br0, Br1;
  Bq0 = *(const short8*)(wbase);
  Bq1 = *(const short8*)(wbase + 32);

  BARRIER();                 // a1l/c1l visible

#define TRW(KB, RAW) do { \
    f4 _a0 = *(const f4*)(&a1l[(KB)*64 + ak0]); \
    f4 _a1 = *(const f4*)(&a1l[(KB)*64 + ak0 + 4]); \
    f4 _c0 = *(const f4*)(&c1l[(KB)*64 + ak0]); \
    f4 _c1 = *(const f4*)(&c1l[(KB)*64 + ak0 + 4]); \
    float _t0 = hclip(_a0[0]*bflo(RAW.x) + _c0[0]); \
    float _t1 = hclip(_a0[1]*bfhi(RAW.x) + _c0[1]); \
    float _t2 = hclip(_a0[2]*bflo(RAW.y) + _c0[2]); \
    float _t3 = hclip(_a0[3]*bfhi(RAW.y) + _c0[3]); \
    float _t4 = hclip(_a1[0]*bflo(RAW.z) + _c1[0]); \
    float _t5 = hclip(_a1[1]*bfhi(RAW.z) + _c1[1]); \
    float _t6 = hclip(_a1[2]*bflo(RAW.w) + _c1[2]); \
    float _t7 = hclip(_a1[3]*bfhi(RAW.w) + _c1[3]); \
    u4 _v; \
    _v.x = f2bf(_t0) | (f2bf(_t1) << 16); \
    _v.y = f2bf(_t2) | (f2bf(_t3) << 16); \
    _v.z = f2bf(_t4) | (f2bf(_t5) << 16); \
    _v.w = f2bf(_t6) | (f2bf(_t7) << 16); \
    *(u4*)(lds + (KB)*8192 + aw) = _v; \
  } while(0)

  TRW(0, q0); TRW(1, q1); TRW(2, q2); TRW(3, q3);
#undef TRW
  BARRIER();

  f4 acc[4];
  const f4 z = {0.f, 0.f, 0.f, 0.f};
  #pragma unroll
  for (int i = 0; i < 4; i++) acc[i] = z;

#define LOADB2(P, KB) do { \
    B##P##0 = *(const short8*)(wbase + (KB)*64); \
    B##P##1 = *(const short8*)(wbase + (KB)*64 + 32); \
  } while(0)

#define COMP2(BASE, P) do { \
    const char* _ab = (const char*)(BASE); \
    short8 _af[4][2]; \
    _Pragma("unroll") \
    for (int fm = 0; fm < 4; fm++){ \
      int _m = fm*16 + cl; \
      _af[fm][0] = *(const short8*)(_ab + ((_m*128 + klo*2) ^ ((_m & 7) << 4))); \
      _af[fm][1] = *(const short8*)(_ab + ((_m*128 + (32 + klo)*2) ^ ((_m & 7) << 4))); \
    } \
    _Pragma("unroll") \
    for (int fm = 0; fm < 4; fm++){ \
      acc[fm] = __builtin_amdgcn_mfma_f32_16x16x32_bf16(_af[fm][0], B##P##0, acc[fm], 0, 0, 0); \
      acc[fm] = __builtin_amdgcn_mfma_f32_16x16x32_bf16(_af[fm][1], B##P##1, acc[fm], 0, 0, 0); \
    } \
  } while(0)

  LOADB2(r, 1);
  COMP2(lds,         q);
  LOADB2(q, 2);
  COMP2(lds +  8192, r);
  LOADB2(r, 3);
  COMP2(lds + 16384, q);
  COMP2(lds + 24576, r);
#undef COMP2
#undef LOADB2

  {
    int c = wid*16 + cl;
    float sb = fsign(b2[c]);
    float s = 0.f, q = 0.f;
    #pragma unroll
    for (int fm = 0; fm < 4; fm++){
      int rbase = row0 + fm*16 + g*4;
      #pragma unroll
      for (int i = 0; i < 4; i++){
        float v = acc[fm][i] + sb;
        h2[(size_t)(rbase + i)*128 + c] = (unsigned short)f2bf(v);
        s += v; q += v*v;
      }
    }
    s += __shfl_xor(s, 16, 64); s += __shfl_xor(s, 32, 64);
    q += __shfl_xor(q, 16, 64); q += __shfl_xor(q, 32, 64);
    if (g == 0){
      part2s[c*256 + blockIdx.x] = s;
      part2q[c*256 + blockIdx.x] = q;
    }
  }
}

// ---------------- final: out = clip(BN2(h2)) @ W4^T + b4, BN2 params fused ---------------------
__global__ __launch_bounds__(128) void final_k(
    const unsigned short* __restrict__ h2,
    const float* __restrict__ part2s, const float* __restrict__ part2q,
    const float* __restrict__ g2, const float* __restrict__ be2,
    const float* __restrict__ W4, const float* __restrict__ b4,
    float* __restrict__ out)
{
  __shared__ __align__(16) float W4l[12*128];
  __shared__ __align__(16) float a2l[128];
  __shared__ __align__(16) float c2l[128];
  const int t = threadIdx.x;
  #pragma unroll
  for (int i = 0; i < 3; i++)
    *(f4*)&W4l[(i*128 + t)*4] = *(const f4*)(W4 + (i*128 + t)*4);
  {
    const f4* vs = (const f4*)(part2s + t*256);
    const f4* vq = (const f4*)(part2q + t*256);
    f4 s4 = {0,0,0,0}, q4 = {0,0,0,0};
    #pragma unroll 8
    for (int b = 0; b < 64; b++){ s4 += vs[b]; q4 += vq[b]; }
    float s = s4[0]+s4[1]+s4[2]+s4[3];
    float q = q4[0]+q4[1]+q4[2]+q4[3];
    float mu  = s * (1.f/16384.f);
    float var = q * (1.f/16384.f) - mu*mu;
    float a   = g2[t] * rsqrtf(var + 1e-5f);
    a2l[t] = a;
    c2l[t] = be2[t] - mu*a;
  }
  __syncthreads();

  const int r = blockIdx.x * 128 + t;
  const u4* hp = (const u4*)(h2 + (size_t)r * 128);
  u4 hv0 = hp[0], hv1 = hp[1], hv2 = hp[2],  hv3 = hp[3];
  u4 hv4 = hp[4], hv5 = hp[5], hv6 = hp[6],  hv7 = hp[7];
  u4 hv8 = hp[8], hv9 = hp[9], hv10 = hp[10], hv11 = hp[11];
  u4 hv12 = hp[12], hv13 = hp[13], hv14 = hp[14], hv15 = hp[15];

  float acc[12];
  #pragma unroll
  for (int o = 0; o < 12; o++) acc[o] = b4[o];

#define FPROC(HV, J) do { \
    f4 a0 = *(const f4*)&a2l[(J)*8];     f4 a1 = *(const f4*)&a2l[(J)*8 + 4]; \
    f4 c0 = *(const f4*)&c2l[(J)*8];     f4 c1 = *(const f4*)&c2l[(J)*8 + 4]; \
    float tt0 = hclip(a0[0]*bflo(HV.x) + c0[0]); \
    float tt1 = hclip(a0[1]*bfhi(HV.x) + c0[1]); \
    float tt2 = hclip(a0[2]*bflo(HV.y) + c0[2]); \
    float tt3 = hclip(a0[3]*bfhi(HV.y) + c0[3]); \
    float tt4 = hclip(a1[0]*bflo(HV.z) + c1[0]); \
    float tt5 = hclip(a1[1]*bfhi(HV.z) + c1[1]); \
    float tt6 = hclip(a1[2]*bflo(HV.w) + c1[2]); \
    float tt7 = hclip(a1[3]*bfhi(HV.w) + c1[3]); \
    _Pragma("unroll") \
    for (int o = 0; o < 12; o++){ \
      f4 w0 = *(const f4*)&W4l[o*128 + (J)*8]; \
      f4 w1 = *(const f4*)&W4l[o*128 + (J)*8 + 4]; \
      acc[o] += tt0*w0[0] + tt1*w0[1] + tt2*w0[2] + tt3*w0[3] \
              + tt4*w1[0] + tt5*w1[1] + tt6*w1[2] + tt7*w1[3]; \
    } \
  } while(0)

  FPROC(hv0, 0);  FPROC(hv1, 1);  FPROC(hv2, 2);   FPROC(hv3, 3);
  FPROC(hv4, 4);  FPROC(hv5, 5);  FPROC(hv6, 6);   FPROC(hv7, 7);
  FPROC(hv8, 8);  FPROC(hv9, 9);  FPROC(hv10, 10); FPROC(hv11, 11);
  FPROC(hv12, 12); FPROC(hv13, 13); FPROC(hv14, 14); FPROC(hv15, 15);
#undef FPROC

  #pragma unroll
  for (int o = 0; o < 12; o++) out[(size_t)r*12 + o] = acc[o];
}

// ---------------- launch ----------------
extern "C" void kernel_launch(void* const* d_in, const int* in_sizes, int n_in,
                              void* d_out, int out_size, void* d_ws, size_t ws_size,
                              hipStream_t stream)
{
  const float* x   = (const float*)d_in[0];
  const float* W1  = (const float*)d_in[1];
  const float* b1  = (const float*)d_in[2];
  const float* g1  = (const float*)d_in[3];
  const float* be1 = (const float*)d_in[4];
  const float* W2  = (const float*)d_in[5];
  const float* b2  = (const float*)d_in[6];
  const float* g2  = (const float*)d_in[7];
  const float* be2 = (const float*)d_in[8];
  const float* W4  = (const float*)d_in[9];
  const float* b4  = (const float*)d_in[10];
  float* out = (float*)d_out;

  char* ws = (char*)d_ws;
  unsigned short* h1     = (unsigned short*)(ws);              //  8 MB  [16384,256] bf16
  unsigned short* h2     = (unsigned short*)(ws + 8388608);    //  4 MB  [16384,128] bf16
  unsigned short* w1s    = (unsigned short*)(ws + 12582912);   //  2 MB  [256,4096] bf16
  unsigned short* w2s    = (unsigned short*)(ws + 14680064);   // 64 KB  [128,256] bf16
  float*          part1s = (float*)(ws + 14745600);            // 512 KB [256][512]
  float*          part1q = (float*)(ws + 15269888);            // 512 KB
  float*          part2s = (float*)(ws + 15794176);            // 128 KB [128][256]
  float*          part2q = (float*)(ws + 15925248);            // 128 KB
  float*          ab1    = (float*)(ws + 16056320);            // a1[256], c1[256]

  prep_sign_k<<<528, 256, 0, stream>>>(W1, w1s, W2, w2s);
  gemm1_k<<<256, 512, 0, stream>>>(x, w1s, b1, h1, part1s, part1q);
  params_k<256, 512><<<4, 64, 0, stream>>>(part1s, part1q, g1, be1, ab1);
  gemm2_k<<<256, 512, 0, stream>>>(h1, w2s, b2, ab1, h2, part2s, part2q);
  final_k<<<128, 128, 0, stream>>>(h2, part2s, part2q, g2, be2, W4, b4, out);
}